// Round 9
// baseline (269.274 us; speedup 1.0000x reference)
//
#include <hip/hip_runtime.h>
#include <math.h>

typedef __attribute__((ext_vector_type(8))) short short8;
typedef __attribute__((ext_vector_type(4))) float float4v;
typedef unsigned int uint;

#define BATCH 8
#define SEQ   4096
#define DIM   768
#define HID   512
#define M_TOK (BATCH * SEQ)   // 32768

// ---------- helpers ----------
static __device__ __forceinline__ short f2bf_rne(float x) {
    unsigned int u = __float_as_uint(x);
    unsigned int r = (u + 0x7FFFu + ((u >> 16) & 1u)) >> 16;   // RNE
    return (short)r;
}
// pack two floats -> 2 bf16 (truncate) in ONE v_perm_b32. lo=bf16(a), hi=bf16(b).
static __device__ __forceinline__ uint pack_bf2(float a, float b) {
    return __builtin_amdgcn_perm(__float_as_uint(b), __float_as_uint(a), 0x07060302u);
}
union FragU { uint u[4]; short8 s; };

// ---------- prep: W1 [DIM][HID] fp32 -> W1T in B-FRAGMENT-LINEAR bf16 chunks.
// Chunk id = h*24 + kg  (h = n/16 in 0..31, kg = k/32 in 0..23); chunk = 1 KB where
// lane l=q*16+r holds 16 B = bf16 values W1[k = kg*32+q*8+j][n = h*16+r], j=0..7.
// A wave's MFMA B-fragment load is then ONE coalesced 16B/lane load. (Verified R8.)
__global__ __launch_bounds__(64) void prep_kernel(const float* __restrict__ W1,
                                                  short* __restrict__ W1T) {
    const int bid = blockIdx.x;                 // 768 chunks
    const int h = bid / 24, kg = bid % 24;
    const int lane = threadIdx.x & 63, q = lane >> 4, r = lane & 15;
    float f[8];
#pragma unroll
    for (int j = 0; j < 8; j++)
        f[j] = W1[(size_t)(kg * 32 + q * 8 + j) * HID + h * 16 + r];
    uint u[4];
#pragma unroll
    for (int i = 0; i < 4; i++)
        u[i] = ((uint)(unsigned short)f2bf_rne(f[2 * i + 1]) << 16) |
               (uint)(unsigned short)f2bf_rne(f[2 * i]);
    uint* dst = (uint*)(W1T + (size_t)bid * 512) + lane * 4;
    dst[0] = u[0]; dst[1] = u[1]; dst[2] = u[2]; dst[3] = u[3];
}

// ---------- MLP: ZERO-STAGING register GEMM. Block = 128M x 512N, 8 waves
// (2M x 4N, each 64x128, acc[4][8]); grid 256. No LDS in the loop, no barriers,
// no DMA, no inline asm: A fragments load straight from global (per (mf,r) row,
// the 4 q-lanes cover one full 128B line; 4 wc-sibling waves reread it within
// ~100cy -> L1 hits; A itself is L3-resident across bench iters — FETCH_SIZE
// has shown ~52MB all along), B fragments load from the L2-resident 786KB
// fragment-linear W1T (one coalesced 16B/lane load each). Compiler manages all
// vmcnt/lgkmcnt and cross-iteration pipelining; waves hide latency via m114
// wave-level overlap, not barriers. This removes the global_load_lds path whose
// measured ceiling (~5.5TB/s chip) bound rounds 0-7.
__global__ __launch_bounds__(512, 2) void mlp_kernel(const float* __restrict__ A,
                                                     const short* __restrict__ BT,
                                                     const float* __restrict__ b1,
                                                     const float* __restrict__ W2,
                                                     float* __restrict__ logits) {
    __shared__ float red[512];
    const int tid = threadIdx.x, wave = tid >> 6, lane = tid & 63;
    const int q = lane >> 4, r = lane & 15;
    const int wr = wave >> 2, wc = wave & 3;     // 2x4 wave grid
    const int m0 = blockIdx.x * 128;

    // per-wave A row pointers (lane's row for each mf), k-base q*8
    const float* aRow[4];
#pragma unroll
    for (int mf = 0; mf < 4; mf++)
        aRow[mf] = A + (size_t)(m0 + wr * 64 + mf * 16 + r) * DIM + q * 8;
    // per-wave B chunk base (this wave's col-slice), lane offset folded in
    const short* bBase[8];
#pragma unroll
    for (int nf = 0; nf < 8; nf++)
        bBase[nf] = BT + ((size_t)(wc * 8 + nf) * 24) * 512 + lane * 8;

    float4v acc[4][8] = {};

    for (int t = 0; t < 12; ++t) {               // BK=64 per t, two K=32 halves
#pragma unroll
        for (int kk = 0; kk < 2; ++kk) {
            const int kg = t * 2 + kk;           // 32-wide k-group 0..23
            short8 bfr[8];
#pragma unroll
            for (int nf = 0; nf < 8; nf++)
                bfr[nf] = *(const short8*)(bBase[nf] + kg * 512);
#pragma unroll
            for (int mf = 0; mf < 4; mf++) {
                const float* ap = aRow[mf] + kg * 32;
                float4v f0 = *(const float4v*)(ap);
                float4v f1 = *(const float4v*)(ap + 4);
                FragU af;
                af.u[0] = pack_bf2(f0[0], f0[1]);
                af.u[1] = pack_bf2(f0[2], f0[3]);
                af.u[2] = pack_bf2(f1[0], f1[1]);
                af.u[3] = pack_bf2(f1[2], f1[3]);
#pragma unroll
                for (int nf = 0; nf < 8; nf++)
                    acc[mf][nf] = __builtin_amdgcn_mfma_f32_16x16x32_bf16(
                        af.s, bfr[nf], acc[mf][nf], 0, 0, 0);
            }
        }
    }

    // epilogue: h = relu(acc + b1); partial over this wave's 128 cols
    float b1v[8], w2v[8];
#pragma unroll
    for (int nf = 0; nf < 8; nf++) {
        int gc = wc * 128 + nf * 16 + r;
        b1v[nf] = b1[gc];
        w2v[nf] = W2[gc];
    }
#pragma unroll
    for (int mf = 0; mf < 4; mf++)
#pragma unroll
        for (int v = 0; v < 4; v++) {
            float pp = 0.f;
#pragma unroll
            for (int nf = 0; nf < 8; nf++) {
                float hh = acc[mf][nf][v] + b1v[nf];
                hh = hh > 0.f ? hh : 0.f;
                pp += hh * w2v[nf];
            }
#pragma unroll
            for (int off = 1; off < 16; off <<= 1) pp += __shfl_xor(pp, off, 64);
            if (r == 0) red[wc * 128 + wr * 64 + mf * 16 + q * 4 + v] = pp;
        }
    __syncthreads();
    if (tid < 128) {
        logits[m0 + tid] = red[tid] + red[128 + tid] + red[256 + tid] + red[384 + tid];
    }
}

// ---------- boundary: logits -> hard bits, per-batch scan -> segment starts ----------
__global__ __launch_bounds__(1024) void boundary_kernel(const float* __restrict__ logits,
                                                        const float* __restrict__ b2p,
                                                        const float* __restrict__ noise,
                                                        int* __restrict__ starts,   // [BATCH][SEQ+1]
                                                        int* __restrict__ nseg,     // [BATCH]
                                                        int* __restrict__ nbcount) {// [BATCH]
    const int b = blockIdx.x, tid = threadIdx.x;
    const int base = tid * 4;
    const float b2 = b2p[0];
    int h[4], c = 0;
#pragma unroll
    for (int j = 0; j < 4; j++) {
        int l = base + j;
        float u = noise[b * SEQ + l];
        float lg = logits[b * SEQ + l] + b2 + logf(u) - log1pf(-u);
        h[j] = (lg > 0.f) ? 1 : 0;
        c += h[j];
    }
    const int lane = tid & 63, wid = tid >> 6;
    int inc = c;
    for (int off = 1; off < 64; off <<= 1) {
        int t = __shfl_up(inc, off, 64);
        if (lane >= off) inc += t;
    }
    __shared__ int wtot[16], woff[16], extra[2];
    if (lane == 63) wtot[wid] = inc;
    if (tid == 1023) extra[0] = h[3];
    __syncthreads();
    if (tid == 0) {
        int s = 0;
        for (int i = 0; i < 16; i++) { woff[i] = s; s += wtot[i]; }
        extra[1] = s;
    }
    __syncthreads();
    int run = (inc - c) + woff[wid];       // exclusive prefix of hard bits
#pragma unroll
    for (int j = 0; j < 4; j++) {
        int l = base + j;
        if (h[j]) {
            run++;
            if (l < SEQ - 1) starts[b * (SEQ + 1) + run] = l + 1;
        }
    }
    if (tid == 0) {
        int total = extra[1];
        int ns = total + (extra[0] ? 0 : 1);
        starts[b * (SEQ + 1)] = 0;
        starts[b * (SEQ + 1) + ns] = SEQ;
        nseg[b] = ns;
        nbcount[b] = total;
    }
}

// ---------- pool: 4 waves/block, one wave per slot; 2-way row unroll; NT stores ----------
__global__ __launch_bounds__(256) void pool_kernel(const float* __restrict__ hidden,
                                                   const int* __restrict__ starts,
                                                   const int* __restrict__ nseg,
                                                   float* __restrict__ out) {
    const int wid = threadIdx.x >> 6, lane = threadIdx.x & 63;
    const int s = blockIdx.x * 4 + wid, b = blockIdx.y;
    float* orow = out + (size_t)(b * SEQ + s) * DIM;
    float4v a0 = {0.f, 0.f, 0.f, 0.f}, a1 = a0, a2 = a0;
    const int ns = nseg[b];
    if (s < ns) {
        const int st = starts[b * (SEQ + 1) + s];
        const int en = starts[b * (SEQ + 1) + s + 1];
        float4v c0 = a0, c1 = a0, c2 = a0;
        const float* hbase = hidden + (size_t)(b * SEQ) * DIM;
        int row = st;
        for (; row + 2 <= en; row += 2) {
            const float* h0 = hbase + (size_t)row * DIM;
            const float* h1 = h0 + DIM;
            a0 += *(const float4v*)(h0 + lane * 4);
            a1 += *(const float4v*)(h0 + (lane + 64) * 4);
            a2 += *(const float4v*)(h0 + (lane + 128) * 4);
            c0 += *(const float4v*)(h1 + lane * 4);
            c1 += *(const float4v*)(h1 + (lane + 64) * 4);
            c2 += *(const float4v*)(h1 + (lane + 128) * 4);
        }
        if (row < en) {
            const float* h0 = hbase + (size_t)row * DIM;
            a0 += *(const float4v*)(h0 + lane * 4);
            a1 += *(const float4v*)(h0 + (lane + 64) * 4);
            a2 += *(const float4v*)(h0 + (lane + 128) * 4);
        }
        a0 += c0; a1 += c1; a2 += c2;
        const float invc = 1.f / (float)(en - st);
        a0 *= invc; a1 *= invc; a2 *= invc;
    }
    __builtin_nontemporal_store(a0, (float4v*)(orow + lane * 4));
    __builtin_nontemporal_store(a1, (float4v*)(orow + (lane + 64) * 4));
    __builtin_nontemporal_store(a2, (float4v*)(orow + (lane + 128) * 4));
}

// ---------- finalize: loss / num_boundaries / total_positions ----------
__global__ void finalize_kernel(const int* __restrict__ nbcount, float* __restrict__ tail) {
    int nb = 0;
    for (int i = 0; i < BATCH; i++) nb += nbcount[i];
    float ratio = (float)nb / (float)M_TOK;
    float d = fabsf(ratio - 0.25f) - 0.05f;    // PRIOR + 0.05 = 0.25, margin 0.05
    tail[0] = d > 0.f ? d : 0.f;
    tail[1] = (float)nb;
    tail[2] = (float)M_TOK;
}

// ---------- launch ----------
extern "C" void kernel_launch(void* const* d_in, const int* in_sizes, int n_in,
                              void* d_out, int out_size, void* d_ws, size_t ws_size,
                              hipStream_t stream) {
    const float* hidden = (const float*)d_in[0];
    const float* W1     = (const float*)d_in[1];
    const float* b1     = (const float*)d_in[2];
    const float* W2     = (const float*)d_in[3];
    const float* b2     = (const float*)d_in[4];
    const float* noise  = (const float*)d_in[5];

    char* ws = (char*)d_ws;
    short* W1T    = (short*)(ws);                    // 786432 B (fragment-linear)
    float* logits = (float*)(ws + 786432);           // 131072 B
    int*   starts = (int*)(ws + 917504);             // 131104 B
    int*   nseg   = (int*)(ws + 917504 + 131104);    // 32 B
    int*   nbcount = nseg + 8;                       // 32 B
    float* out    = (float*)d_out;

    prep_kernel<<<768, 64, 0, stream>>>(W1, W1T);
    mlp_kernel<<<M_TOK / 128, 512, 0, stream>>>(hidden, W1T, b1, W2, logits);
    boundary_kernel<<<BATCH, 1024, 0, stream>>>(logits, b2, noise, starts, nseg, nbcount);
    pool_kernel<<<dim3(SEQ / 4, BATCH), 256, 0, stream>>>(hidden, starts, nseg, out);
    finalize_kernel<<<1, 1, 0, stream>>>(nbcount, out + (size_t)M_TOK * DIM);
}